// Round 1
// baseline (117.705 us; speedup 1.0000x reference)
//
#include <hip/hip_runtime.h>
#include <float.h>

// CropRoi: for each proposal n and channel c, crop f[b, c] to the box
// [c0, c1) per axis (computed from center/side, scale 4, clamped to [0,32])
// and adaptive-max-pool to 7x7x7.
//
// One thread per output element (N*C*343 = 2,107,392). Output layout
// (n, c, i, j, k) with k fastest -> coalesced stores; neighboring threads
// read overlapping w-rows -> good L1/L2 locality. f is 32 MB, fits in L2/L3.

__global__ void crop_roi_kernel(const float* __restrict__ f,
                                const float* __restrict__ props,
                                float* __restrict__ out,
                                int C, int total) {
    const int F = 32;        // feature spatial dim
    const int DIMS = 32;     // dims_max = 128 / SCALE
    int t = blockIdx.x * blockDim.x + threadIdx.x;
    if (t >= total) return;

    int k = t % 7;
    int j = (t / 7) % 7;
    int i = (t / 49) % 7;
    int c = (t / 343) % C;
    int n = t / (343 * C);

    const float* p = props + (size_t)n * 8;
    int b = (int)p[0];

    int c0[3], c1[3];
#pragma unroll
    for (int ax = 0; ax < 3; ++ax) {
        float ce = p[2 + ax];
        float sd = p[5 + ax];
        // (ce - sd/2) / 4 : both ops match JAX f32 arithmetic exactly
        int lo = (int)floorf((ce - sd * 0.5f) * 0.25f);
        int hi = (int)ceilf((ce + sd * 0.5f) * 0.25f);
        lo = lo > 0 ? lo : 0;
        hi = hi < DIMS ? hi : DIMS;
        c0[ax] = lo;
        c1[ax] = hi;
    }
    int L0 = c1[0] - c0[0];
    int L1 = c1[1] - c0[1];
    int L2 = c1[2] - c0[2];

    // segment windows (integer floor/ceil divides; L >= 0)
    int ds = c0[0] + (i * L0) / 7;
    int de = c0[0] + ((i + 1) * L0 + 6) / 7;
    int hs = c0[1] + (j * L1) / 7;
    int he = c0[1] + ((j + 1) * L1 + 6) / 7;
    int ws = c0[2] + (k * L2) / 7;
    int we = c0[2] + ((k + 1) * L2 + 6) / 7;

    float m = -FLT_MAX;  // == jnp.finfo(float32).min
    const float* base = f + ((size_t)b * C + c) * (F * F * F);
    for (int d = ds; d < de; ++d) {
        for (int h = hs; h < he; ++h) {
            const float* row = base + (d * F + h) * F;
            for (int w = ws; w < we; ++w) {
                m = fmaxf(m, row[w]);
            }
        }
    }
    out[t] = m;
}

extern "C" void kernel_launch(void* const* d_in, const int* in_sizes, int n_in,
                              void* d_out, int out_size, void* d_ws, size_t ws_size,
                              hipStream_t stream) {
    const float* f = (const float*)d_in[0];
    // d_in[1] = inputs (only shape used by reference; dims_max = 32 hardcoded)
    const float* props = (const float*)d_in[2];
    // d_in[3] = cls_ind (unused by reference)

    int N = in_sizes[2] / 8;          // proposals are (N, 8)
    int C = out_size / (N * 343);     // outputs are (N, C, 7, 7, 7)
    int total = out_size;

    int threads = 256;
    int blocks = (total + threads - 1) / threads;
    crop_roi_kernel<<<blocks, threads, 0, stream>>>(f, props, (float*)d_out, C, total);
}